// Round 1
// 5215.742 us; speedup vs baseline: 1.0200x; 1.0200x over previous
//
#include <hip/hip_runtime.h>
#include <stdint.h>

static const int T_ = 50;
static const int B_ = 512;
static const int BEL = 1024;
static const int S_ = 256;
static const int A_ = 32;
static const int EI_ = 1024;
static const int ES_ = 256;

typedef __attribute__((ext_vector_type(8))) short bf16x8;
typedef __attribute__((ext_vector_type(4))) float f32x4;

__device__ __forceinline__ short f2bf(float f) {
  union { float f; uint32_t u; } cv; cv.f = f;
  uint32_t u = cv.u;
  u = (u + 0x7fffu + ((u >> 16) & 1u)) >> 16;   // RNE
  return (short)u;
}
__device__ __forceinline__ float bf2f(short s) {
  union { uint32_t u; float f; } cv;
  cv.u = ((uint32_t)(uint16_t)s) << 16;
  return cv.f;
}
__device__ __forceinline__ float softplusf(float x) {
  return (x > 20.f) ? x : log1pf(expf(x));
}

// async global->LDS, 16B per lane, wave-uniform LDS base + lane*16
#define GLL16(gp, lp)                                                        \
  __builtin_amdgcn_global_load_lds(                                          \
      (const __attribute__((address_space(1))) void*)(gp),                   \
      (__attribute__((address_space(3))) void*)(lp), 16, 0, 0)

// d_out layout (flat concat, fp32)
#define SZ_BEL_ALL (50ull * 512ull * 1024ull)
#define SZ_TBS     (50ull * 512ull * 256ull)
#define OFF_PS  (SZ_BEL_ALL)
#define OFF_PM  (OFF_PS + SZ_TBS)
#define OFF_PSD (OFF_PM + SZ_TBS)
#define OFF_QS  (OFF_PSD + SZ_TBS)
#define OFF_QM  (OFF_QS + SZ_TBS)
#define OFF_QSD (OFF_QM + SZ_TBS)

// ---------------- conversion fp32 -> bf16 (4/thread) ----------------
__global__ void k_convert(const float* __restrict__ src, short* __restrict__ dst, int n) {
  int i = (blockIdx.x * blockDim.x + threadIdx.x) * 4;
  if (i >= n) return;
  float4 v = *(const float4*)(src + i);
  short4 o;
  o.x = f2bf(v.x); o.y = f2bf(v.y); o.z = f2bf(v.z); o.w = f2bf(v.w);
  *(short4*)(dst + i) = o;
}

// ---------------- init: belief0_bf + st0 = prev_state * nt0 ----------------
__global__ void k_init(const float* __restrict__ prev_belief, const float* __restrict__ prev_state,
                       const float* __restrict__ nt0,
                       short* __restrict__ belief0_bf, short* __restrict__ st_bf) {
  int i = blockIdx.x * blockDim.x + threadIdx.x;
  if (i < B_ * BEL) {
    belief0_bf[i] = f2bf(prev_belief[i]);
  } else {
    int k = i - B_ * BEL;
    if (k < B_ * S_) {
      int b = k / S_;
      st_bf[k] = f2bf(prev_state[k] * nt0[b]);
    }
  }
}

// ---------------- batched prior-head post (after loop) ----------------
// lsp: [25600, 512] fp32 (loc | scale_pre). 4 cols/thread.
__global__ void k_prior_post(const float* __restrict__ lsp, float* __restrict__ out) {
  int i = blockIdx.x * blockDim.x + threadIdx.x;   // over 25600*64
  int r = i >> 6;
  int j4 = (i & 63) * 4;
  if (r >= T_ * B_) return;
  float4 loc = *(const float4*)(lsp + (size_t)r * 512 + j4);
  float4 sc  = *(const float4*)(lsp + (size_t)r * 512 + 256 + j4);
  float4 psd;
  psd.x = softplusf(sc.x) + 0.1f;
  psd.y = softplusf(sc.y) + 0.1f;
  psd.z = softplusf(sc.z) + 0.1f;
  psd.w = softplusf(sc.w) + 0.1f;
  size_t tb = (size_t)r * 256 + j4;
  *(float4*)(out + OFF_PS + tb)  = loc;
  *(float4*)(out + OFF_PM + tb)  = loc;
  *(float4*)(out + OFF_PSD + tb) = psd;
}

// ---------------- generic bf16 MFMA GEMM (double-buffered K loop) ----------------
// out = act(A[M,K(lda)] @ W[N,K(ldw)]^T + bias + Cadd)
struct Job {
  const short* A;      // [M,*] bf16, row stride lda
  int lda;
  const short* W;      // [N,*] bf16, row stride ldw
  int ldw;
  const float* bias;   // [N] fp32 or null
  const short* Cadd;   // bf16 [M,N] per-element add, or null
  float* outF;         // fp32 [M,N] or null
  short* outB;         // bf16 [M,N] or null
  int K;
  int relu;
};
struct Jobs { Job j[3]; };

template <int BM, int BN>
__global__ __launch_bounds__(256) void k_gemm(Jobs jobs, int N) {
  Job jb = jobs.j[blockIdx.z];
  const int tid = threadIdx.x;
  const int wave = tid >> 6;
  const int lane = tid & 63;
  const int quad = lane >> 4;
  const int r16 = lane & 15;
  const int mBase = blockIdx.y * BM;
  const int nBase = blockIdx.x * BN;
  const int K = jb.K;
  const int lda = jb.lda;
  const int ldw = jb.ldw;

  __shared__ short As[2][BM * 32];
  __shared__ short Bs[2][BN * 32];

  constexpr int WM = BM / 2, WN = BN / 2;
  constexpr int TM = WM / 16, TN = WN / 16;
  const int waveM = (wave >> 1) * WM;
  const int waveN = (wave & 1) * WN;

  f32x4 acc[TM][TN];
#pragma unroll
  for (int a = 0; a < TM; ++a)
#pragma unroll
    for (int b = 0; b < TN; ++b)
      acc[a][b] = (f32x4){0.f, 0.f, 0.f, 0.f};

  const short* Aptr = jb.A + (size_t)mBase * lda;
  const short* Wptr = jb.W + (size_t)nBase * ldw;
  const int srow = tid >> 2;          // 0..63 within a 64-row chunk
  const int scol = (tid & 3) * 8;     // 0,8,16,24

  auto stage = [&](int buf, int k0) {
#pragma unroll
    for (int c = 0; c < BM / 64; ++c) {
      const short* g = Aptr + (size_t)(c * 64 + srow) * lda + k0 + scol;
      GLL16(g, &As[buf][c * 2048 + wave * 512]);
    }
#pragma unroll
    for (int c = 0; c < BN / 64; ++c) {
      const short* g = Wptr + (size_t)(c * 64 + srow) * ldw + k0 + scol;
      GLL16(g, &Bs[buf][c * 2048 + wave * 512]);
    }
  };

  const int nk = K >> 5;
  stage(0, 0);
  __syncthreads();   // drains vmcnt(0) before s_barrier

  for (int kt = 0; kt < nk; ++kt) {
    const int cur = kt & 1;
    if (kt + 1 < nk) stage(cur ^ 1, (kt + 1) << 5);   // overlap with compute

    bf16x8 af[TM], bfr[TN];
#pragma unroll
    for (int mi = 0; mi < TM; ++mi)
      af[mi] = *(const bf16x8*)(&As[cur][(waveM + mi * 16 + r16) * 32 + quad * 8]);
#pragma unroll
    for (int ni = 0; ni < TN; ++ni)
      bfr[ni] = *(const bf16x8*)(&Bs[cur][(waveN + ni * 16 + r16) * 32 + quad * 8]);
#pragma unroll
    for (int mi = 0; mi < TM; ++mi)
#pragma unroll
      for (int ni = 0; ni < TN; ++ni)
        acc[mi][ni] = __builtin_amdgcn_mfma_f32_16x16x32_bf16(af[mi], bfr[ni], acc[mi][ni], 0, 0, 0);

    if (kt + 1 < nk) __syncthreads();  // reads of cur done; drains next-stage DMA
  }

#pragma unroll
  for (int mi = 0; mi < TM; ++mi) {
#pragma unroll
    for (int ni = 0; ni < TN; ++ni) {
#pragma unroll
      for (int reg = 0; reg < 4; ++reg) {
        int row = mBase + waveM + mi * 16 + quad * 4 + reg;
        int col = nBase + waveN + ni * 16 + r16;
        float v = acc[mi][ni][reg];
        if (jb.bias) v += jb.bias[col];
        if (jb.Cadd) v += bf2f(jb.Cadd[(size_t)row * N + col]);
        if (jb.relu) v = v > 0.f ? v : 0.f;
        if (jb.outF) jb.outF[(size_t)row * N + col] = v;
        if (jb.outB) jb.outB[(size_t)row * N + col] = f2bf(v);
      }
    }
  }
}

// ---------------- fused gates GEMM + GRU ----------------
// Block: 64 batch rows x 32 belief cols; computes r,z,n tiles of BOTH
// gi = hidden@W_ih^T and gh = belief_old@W_hh^T, then GRU epilogue.
// grid (32, 8) = 256 blocks, 256 threads (2x2 waves, WM=32, WN=16).
__global__ __launch_bounds__(256) void k_gates_gru(
    const short* __restrict__ hidden,      // [512,1024] bf16
    const short* __restrict__ belief_old,  // [512,1024] bf16 (t-1)
    const short* __restrict__ Wih,         // [3072,1024] bf16
    const short* __restrict__ Whh,         // [3072,1024] bf16
    const float* __restrict__ b_ih, const float* __restrict__ b_hh,
    const float* __restrict__ h_old,       // [512,1024] fp32 (t-1)
    float* __restrict__ beliefs_out,       // fp32 [512,1024] = out + t*B*BEL
    short* __restrict__ belief_bf_new) {   // bf16 [512,1024] (t)
  const int tid = threadIdx.x;
  const int wave = tid >> 6;
  const int lane = tid & 63;
  const int quad = lane >> 4;
  const int r16 = lane & 15;
  const int nBase = blockIdx.x * 32;   // belief col block
  const int mBase = blockIdx.y * 64;   // batch row block
  const int waveM = (wave >> 1) * 32;
  const int waveN = (wave & 1) * 16;

  __shared__ short Ah[2][64 * 32];
  __shared__ short Ab[2][64 * 32];
  __shared__ short Wt[2][6][32 * 32];  // 0..2: W_ih r/z/n ; 3..5: W_hh r/z/n

  f32x4 acc[6][2];
#pragma unroll
  for (int g = 0; g < 6; ++g)
#pragma unroll
    for (int mi = 0; mi < 2; ++mi)
      acc[g][mi] = (f32x4){0.f, 0.f, 0.f, 0.f};

  const int srow = tid >> 2;            // 0..63
  const int scol = (tid & 3) * 8;
  const int wrow = (tid & 127) >> 2;    // 0..31
  const int wsel = tid >> 7;            // 0|1 (wave-uniform)

  auto stage = [&](int buf, int k0) {
    GLL16(hidden + (size_t)(mBase + srow) * 1024 + k0 + scol, &Ah[buf][wave * 512]);
    GLL16(belief_old + (size_t)(mBase + srow) * 1024 + k0 + scol, &Ab[buf][wave * 512]);
#pragma unroll
    for (int p = 0; p < 3; ++p) {
      const int gidx = 2 * p + wsel;
      const short* Wsrc = (gidx < 3) ? Wih : Whh;
      const int gofs = (gidx % 3) * 1024;
      GLL16(Wsrc + (size_t)(nBase + gofs + wrow) * 1024 + k0 + scol,
            &Wt[buf][gidx][(wave & 1) * 512]);
    }
  };

  stage(0, 0);
  __syncthreads();

  for (int kt = 0; kt < 32; ++kt) {
    const int cur = kt & 1;
    if (kt + 1 < 32) stage(cur ^ 1, (kt + 1) << 5);

    bf16x8 ah[2], ab[2], wf[6];
#pragma unroll
    for (int mi = 0; mi < 2; ++mi) {
      ah[mi] = *(const bf16x8*)(&Ah[cur][(waveM + mi * 16 + r16) * 32 + quad * 8]);
      ab[mi] = *(const bf16x8*)(&Ab[cur][(waveM + mi * 16 + r16) * 32 + quad * 8]);
    }
#pragma unroll
    for (int g = 0; g < 6; ++g)
      wf[g] = *(const bf16x8*)(&Wt[cur][g][(waveN + r16) * 32 + quad * 8]);

#pragma unroll
    for (int g = 0; g < 3; ++g)
#pragma unroll
      for (int mi = 0; mi < 2; ++mi)
        acc[g][mi] = __builtin_amdgcn_mfma_f32_16x16x32_bf16(ah[mi], wf[g], acc[g][mi], 0, 0, 0);
#pragma unroll
    for (int g = 0; g < 3; ++g)
#pragma unroll
      for (int mi = 0; mi < 2; ++mi)
        acc[3 + g][mi] = __builtin_amdgcn_mfma_f32_16x16x32_bf16(ab[mi], wf[3 + g], acc[3 + g][mi], 0, 0, 0);

    if (kt + 1 < 32) __syncthreads();
  }

  // GRU epilogue — biases depend only on col, hoist per lane
  const int col = nBase + waveN + r16;
  const float bir = b_ih[col], biz = b_ih[1024 + col], bin_ = b_ih[2048 + col];
  const float bhr = b_hh[col], bhz = b_hh[1024 + col], bhn = b_hh[2048 + col];
#pragma unroll
  for (int mi = 0; mi < 2; ++mi) {
#pragma unroll
    for (int reg = 0; reg < 4; ++reg) {
      int row = mBase + waveM + mi * 16 + quad * 4 + reg;
      float ir = acc[0][mi][reg] + bir;
      float iz = acc[1][mi][reg] + biz;
      float in_ = acc[2][mi][reg] + bin_;
      float hr = acc[3][mi][reg] + bhr;
      float hz = acc[4][mi][reg] + bhz;
      float hn = acc[5][mi][reg] + bhn;
      float rr = 1.f / (1.f + expf(-(ir + hr)));
      float zz = 1.f / (1.f + expf(-(iz + hz)));
      float nn = tanhf(in_ + rr * hn);
      float h = h_old[(size_t)row * 1024 + col];
      float hnew = (1.f - zz) * nn + zz * h;
      beliefs_out[(size_t)row * 1024 + col] = hnew;
      belief_bf_new[(size_t)row * 1024 + col] = f2bf(hnew);
    }
  }
}

// ---------------- fused heads2 GEMMs + softplus + PoE + st update ----------------
// Block: 64 batch rows x 32 state cols; 4 tiles: (ei loc, ei scale, es loc, es scale).
// Wave owns loc tile at col j and scale tile at col j+256 -> PoE is register-local.
// grid (8, 8) = 64 blocks, 256 threads (2x2 waves, WM=32, WJ=16).
__global__ __launch_bounds__(256) void k_heads2_poe(
    const short* __restrict__ eih,   // [512,1024] bf16
    const short* __restrict__ esh,   // [512,1024] bf16
    const short* __restrict__ Wei2,  // [512,1024] bf16
    const short* __restrict__ Wes2,  // [512,1024] bf16
    const float* __restrict__ b_ei2, const float* __restrict__ b_es2,
    const float* __restrict__ nt_next,  // [B] or null
    short* __restrict__ st_bf, float* __restrict__ out, int t) {
  const int tid = threadIdx.x;
  const int wave = tid >> 6;
  const int lane = tid & 63;
  const int quad = lane >> 4;
  const int r16 = lane & 15;
  const int jBase = blockIdx.x * 32;   // state col block (0..224)
  const int mBase = blockIdx.y * 64;   // batch row block
  const int waveM = (wave >> 1) * 32;
  const int waveJ = (wave & 1) * 16;

  __shared__ short Ai[2][64 * 32];
  __shared__ short An[2][64 * 32];
  __shared__ short Wp[2][4][32 * 32];  // 0: ei loc, 1: ei scale, 2: es loc, 3: es scale

  f32x4 acc[4][2];
#pragma unroll
  for (int g = 0; g < 4; ++g)
#pragma unroll
    for (int mi = 0; mi < 2; ++mi)
      acc[g][mi] = (f32x4){0.f, 0.f, 0.f, 0.f};

  const int srow = tid >> 2;
  const int scol = (tid & 3) * 8;
  const int wrow = (tid & 127) >> 2;
  const int wsel = tid >> 7;

  auto stage = [&](int buf, int k0) {
    GLL16(eih + (size_t)(mBase + srow) * 1024 + k0 + scol, &Ai[buf][wave * 512]);
    GLL16(esh + (size_t)(mBase + srow) * 1024 + k0 + scol, &An[buf][wave * 512]);
#pragma unroll
    for (int p = 0; p < 2; ++p) {
      const int gidx = 2 * p + wsel;
      const short* Wsrc = (gidx < 2) ? Wei2 : Wes2;
      const int rofs = (gidx & 1) * 256;   // scale rows at +256
      GLL16(Wsrc + (size_t)(rofs + jBase + wrow) * 1024 + k0 + scol,
            &Wp[buf][gidx][(wave & 1) * 512]);
    }
  };

  stage(0, 0);
  __syncthreads();

  for (int kt = 0; kt < 32; ++kt) {
    const int cur = kt & 1;
    if (kt + 1 < 32) stage(cur ^ 1, (kt + 1) << 5);

    bf16x8 ai[2], an[2], wf[4];
#pragma unroll
    for (int mi = 0; mi < 2; ++mi) {
      ai[mi] = *(const bf16x8*)(&Ai[cur][(waveM + mi * 16 + r16) * 32 + quad * 8]);
      an[mi] = *(const bf16x8*)(&An[cur][(waveM + mi * 16 + r16) * 32 + quad * 8]);
    }
#pragma unroll
    for (int g = 0; g < 4; ++g)
      wf[g] = *(const bf16x8*)(&Wp[cur][g][(waveJ + r16) * 32 + quad * 8]);

#pragma unroll
    for (int mi = 0; mi < 2; ++mi) {
      acc[0][mi] = __builtin_amdgcn_mfma_f32_16x16x32_bf16(ai[mi], wf[0], acc[0][mi], 0, 0, 0);
      acc[1][mi] = __builtin_amdgcn_mfma_f32_16x16x32_bf16(ai[mi], wf[1], acc[1][mi], 0, 0, 0);
      acc[2][mi] = __builtin_amdgcn_mfma_f32_16x16x32_bf16(an[mi], wf[2], acc[2][mi], 0, 0, 0);
      acc[3][mi] = __builtin_amdgcn_mfma_f32_16x16x32_bf16(an[mi], wf[3], acc[3][mi], 0, 0, 0);
    }

    if (kt + 1 < 32) __syncthreads();
  }

  const int jcol = jBase + waveJ + r16;   // 0..255
  const float bil = b_ei2[jcol], bis = b_ei2[256 + jcol];
  const float bsl = b_es2[jcol], bss = b_es2[256 + jcol];
#pragma unroll
  for (int mi = 0; mi < 2; ++mi) {
#pragma unroll
    for (int reg = 0; reg < 4; ++reg) {
      int row = mBase + waveM + mi * 16 + quad * 4 + reg;
      float il = acc[0][mi][reg] + bil;
      float isc = softplusf(acc[1][mi][reg] + bis) + 0.1f;
      float sl = acc[2][mi][reg] + bsl;
      float ssc = softplusf(acc[3][mi][reg] + bss) + 0.1f;
      float pi = 1.f / (isc * isc);
      float ps = 1.f / (ssc * ssc);
      float var = 1.f / (1.f + pi + ps);
      float ql = var * (il * pi + sl * ps);
      float qs = sqrtf(var);
      size_t tb = (size_t)t * B_ * S_ + (size_t)row * 256 + jcol;
      out[OFF_QS + tb]  = ql;
      out[OFF_QM + tb]  = ql;
      out[OFF_QSD + tb] = qs;
      if (nt_next) st_bf[(size_t)row * 256 + jcol] = f2bf(ql * nt_next[row]);
    }
  }
}

extern "C" void kernel_launch(void* const* d_in, const int* in_sizes, int n_in,
                              void* d_out, int out_size, void* d_ws, size_t ws_size,
                              hipStream_t stream) {
  const float* prev_state  = (const float*)d_in[0];
  const float* actions     = (const float*)d_in[1];
  const float* prev_belief = (const float*)d_in[2];
  const float* obs_image   = (const float*)d_in[3];
  const float* obs_sound   = (const float*)d_in[4];
  const float* nonterm     = (const float*)d_in[5];
  const float* W_emb = (const float*)d_in[6];  const float* b_emb = (const float*)d_in[7];
  const float* W_ih  = (const float*)d_in[8];  const float* b_ih  = (const float*)d_in[9];
  const float* W_hh  = (const float*)d_in[10]; const float* b_hh  = (const float*)d_in[11];
  const float* W_s1  = (const float*)d_in[12]; const float* b_s1  = (const float*)d_in[13];
  const float* W_s2  = (const float*)d_in[14]; const float* b_s2  = (const float*)d_in[15];
  const float* W_ei1 = (const float*)d_in[16]; const float* b_ei1 = (const float*)d_in[17];
  const float* W_ei2 = (const float*)d_in[18]; const float* b_ei2 = (const float*)d_in[19];
  const float* W_es1 = (const float*)d_in[20]; const float* b_es1 = (const float*)d_in[21];
  const float* W_es2 = (const float*)d_in[22]; const float* b_es2 = (const float*)d_in[23];
  float* out = (float*)d_out;

  char* base = (char*)d_ws;
  size_t off = 0;
  auto alloc = [&](size_t bytes) -> void* {
    void* p = base + off;
    off += (bytes + 255) & ~(size_t)255;
    return p;
  };

  const size_t TB = (size_t)T_ * B_;  // 25600

  // bf16 weights
  short* Wemb_b = (short*)alloc((size_t)1024 * 288 * 2);
  short* Wih_b  = (short*)alloc((size_t)3072 * 1024 * 2);
  short* Whh_b  = (short*)alloc((size_t)3072 * 1024 * 2);
  short* Ws1_b  = (short*)alloc((size_t)1024 * 1024 * 2);
  short* Ws2_b  = (short*)alloc((size_t)512 * 1024 * 2);
  short* Wei1_b = (short*)alloc((size_t)1024 * 2048 * 2);
  short* Wei2_b = (short*)alloc((size_t)512 * 1024 * 2);
  short* Wes1_b = (short*)alloc((size_t)1024 * 1280 * 2);
  short* Wes2_b = (short*)alloc((size_t)512 * 1024 * 2);
  // bf16 inputs for batched precompute
  short* oi_bf  = (short*)alloc(TB * EI_ * 2);
  short* os_bf  = (short*)alloc(TB * ES_ * 2);
  short* act_bf = (short*)alloc(TB * A_ * 2);
  // precomputed contributions (bf16)
  short* OI_c   = (short*)alloc(TB * 1024 * 2);
  short* OS_c   = (short*)alloc(TB * 1024 * 2);
  short* ACT_c  = (short*)alloc(TB * 1024 * 2);
  // all beliefs in bf16 (feeds heads1 in-loop and batched prior head post-loop)
  short* beliefs_bf = (short*)alloc(TB * BEL * 2);
  // state + per-step activations
  short* belief0_bf = (short*)alloc((size_t)B_ * BEL * 2);
  short* st_bf      = (short*)alloc((size_t)B_ * S_ * 2);
  short* hidden_b   = (short*)alloc((size_t)B_ * 1024 * 2);
  short* eih_b      = (short*)alloc((size_t)B_ * 1024 * 2);
  short* esh_b      = (short*)alloc((size_t)B_ * 1024 * 2);
  // post-loop prior head: alias onto OI_c/OS_c (both dead after the loop)
  short* sh_all  = OS_c;                 // bf16 [25600,1024] = 52.4 MB
  float* lsp_all = (float*)OI_c;         // fp32 [25600,512]  = 52.4 MB

  // fp32 -> bf16 conversions (ws re-poisoned each call)
  struct Conv { const float* s; short* d; size_t n; };
  Conv convs[12] = {
      {W_emb, Wemb_b, 1024 * 288}, {W_ih, Wih_b, 3072 * 1024}, {W_hh, Whh_b, 3072 * 1024},
      {W_s1, Ws1_b, 1024 * 1024},  {W_s2, Ws2_b, 512 * 1024},  {W_ei1, Wei1_b, 1024 * 2048},
      {W_ei2, Wei2_b, 512 * 1024}, {W_es1, Wes1_b, 1024 * 1280}, {W_es2, Wes2_b, 512 * 1024},
      {obs_image, oi_bf, TB * EI_}, {obs_sound, os_bf, TB * ES_}, {actions, act_bf, TB * A_}};
  for (int c = 0; c < 12; ++c) {
    int blocks = (int)((convs[c].n / 4 + 255) / 256);
    k_convert<<<dim3(blocks), dim3(256), 0, stream>>>(convs[c].s, convs[c].d, (int)convs[c].n);
  }

  // batched contributions: OI = oi @ W_ei1[:,1024:]^T + b_ei1 ; OS ; ACT (+b_emb folded)
  {
    Jobs jb{};
    jb.j[0] = Job{oi_bf, 1024, Wei1_b + 1024, 2048, b_ei1, nullptr, nullptr, OI_c, 1024, 0};
    jb.j[1] = jb.j[0]; jb.j[2] = jb.j[0];
    k_gemm<128, 128><<<dim3(8, 200, 1), dim3(256), 0, stream>>>(jb, 1024);
  }
  {
    Jobs jb{};
    jb.j[0] = Job{os_bf, 256, Wes1_b + 1024, 1280, b_es1, nullptr, nullptr, OS_c, 256, 0};
    jb.j[1] = jb.j[0]; jb.j[2] = jb.j[0];
    k_gemm<128, 128><<<dim3(8, 200, 1), dim3(256), 0, stream>>>(jb, 1024);
  }
  {
    Jobs jb{};
    jb.j[0] = Job{act_bf, 32, Wemb_b + 256, 288, b_emb, nullptr, nullptr, ACT_c, 32, 0};
    jb.j[1] = jb.j[0]; jb.j[2] = jb.j[0];
    k_gemm<128, 128><<<dim3(8, 200, 1), dim3(256), 0, stream>>>(jb, 1024);
  }

  k_init<<<dim3((B_ * BEL + B_ * S_) / 256), dim3(256), 0, stream>>>(
      prev_belief, prev_state, nonterm, belief0_bf, st_bf);

  const short* belief_prev_bf = belief0_bf;
  const float* h_prev = prev_belief;
  for (int t = 0; t < T_; ++t) {
    short* belief_t_bf = beliefs_bf + (size_t)t * B_ * BEL;
    float* belief_t_f  = out + (size_t)t * B_ * BEL;
    {  // emb: hidden = relu(st @ W_emb[:,:256]^T + ACT_c[t])
      Jobs jb{};
      jb.j[0] = Job{st_bf, 256, Wemb_b, 288, nullptr, ACT_c + (size_t)t * B_ * 1024,
                    nullptr, hidden_b, 256, 1};
      jb.j[1] = jb.j[0]; jb.j[2] = jb.j[0];
      k_gemm<64, 64><<<dim3(16, 8, 1), dim3(256), 0, stream>>>(jb, 1024);
    }
    // fused gates GEMMs + GRU (reads belief t-1, writes belief t -> no race)
    k_gates_gru<<<dim3(32, 8), dim3(256), 0, stream>>>(
        hidden_b, belief_prev_bf, Wih_b, Whh_b, b_ih, b_hh,
        h_prev, belief_t_f, belief_t_bf);
    {  // head layer 1 (obs part precomputed): eih, esh
      Jobs jb{};
      jb.j[0] = Job{belief_t_bf, 1024, Wei1_b, 2048, nullptr, OI_c + (size_t)t * B_ * 1024,
                    nullptr, eih_b, 1024, 1};
      jb.j[1] = Job{belief_t_bf, 1024, Wes1_b, 1280, nullptr, OS_c + (size_t)t * B_ * 1024,
                    nullptr, esh_b, 1024, 1};
      jb.j[2] = jb.j[0];
      k_gemm<64, 64><<<dim3(16, 8, 2), dim3(256), 0, stream>>>(jb, 1024);
    }
    const float* ntn = (t + 1 < T_) ? (nonterm + (size_t)(t + 1) * B_) : nullptr;
    // fused heads2 + softplus + PoE + q-outputs + next st
    k_heads2_poe<<<dim3(8, 8), dim3(256), 0, stream>>>(
        eih_b, esh_b, Wei2_b, Wes2_b, b_ei2, b_es2, ntn, st_bf, out, t);
    belief_prev_bf = belief_t_bf;
    h_prev = belief_t_f;
  }

  // batched prior head over all 25600 rows (off the critical path)
  {
    Jobs jb{};
    jb.j[0] = Job{beliefs_bf, 1024, Ws1_b, 1024, b_s1, nullptr, nullptr, sh_all, 1024, 1};
    jb.j[1] = jb.j[0]; jb.j[2] = jb.j[0];
    k_gemm<128, 128><<<dim3(8, 200, 1), dim3(256), 0, stream>>>(jb, 1024);
  }
  {
    Jobs jb{};
    jb.j[0] = Job{sh_all, 1024, Ws2_b, 1024, b_s2, nullptr, lsp_all, nullptr, 1024, 0};
    jb.j[1] = jb.j[0]; jb.j[2] = jb.j[0];
    k_gemm<128, 128><<<dim3(4, 200, 1), dim3(256), 0, stream>>>(jb, 512);
  }
  k_prior_post<<<dim3(6400), dim3(256), 0, stream>>>(lsp_all, out);
}